// Round 1
// baseline (927.902 us; speedup 1.0000x reference)
//
#include <hip/hip_runtime.h>

#define S_LEN 4096
#define D_MODEL 1024
#define NHEAD 16
#define DK 64
#define HID 2730
#define HIDP 2752

typedef unsigned short u16;
typedef unsigned int u32;
typedef __bf16 bf16x8 __attribute__((ext_vector_type(8)));
typedef float f32x4 __attribute__((ext_vector_type(4)));

__device__ __forceinline__ float b2f(u16 u) {
    return __builtin_bit_cast(float, (u32)u << 16);
}
__device__ __forceinline__ u16 f2b(float f) {
    u32 u = __builtin_bit_cast(u32, f);
    u += 0x7FFF + ((u >> 16) & 1);   // round-to-nearest-even
    return (u16)(u >> 16);
}

// ---------------------------------------------------------------------------
// RMSNorm: one block per row (D=1024), fp32 in -> bf16 out
// ---------------------------------------------------------------------------
__global__ __launch_bounds__(256)
void rmsnorm_k(const float* __restrict__ x, const float* __restrict__ w,
               u16* __restrict__ out) {
    const int row = blockIdx.x;
    const int tid = threadIdx.x;
    const float4 v = ((const float4*)(x + (size_t)row * D_MODEL))[tid];
    float ss = v.x * v.x + v.y * v.y + v.z * v.z + v.w * v.w;
    for (int o = 32; o; o >>= 1) ss += __shfl_down(ss, o);
    __shared__ float red[4];
    if ((tid & 63) == 0) red[tid >> 6] = ss;
    __syncthreads();
    const float tot = red[0] + red[1] + red[2] + red[3];
    const float rs = rsqrtf(tot * (1.0f / D_MODEL) + 1e-6f);
    const float4 wv = ((const float4*)w)[tid];
    u16* op = out + (size_t)row * D_MODEL + tid * 4;
    u32 p0 = (u32)f2b(v.x * rs * wv.x) | ((u32)f2b(v.y * rs * wv.y) << 16);
    u32 p1 = (u32)f2b(v.z * rs * wv.z) | ((u32)f2b(v.w * rs * wv.w) << 16);
    uint2 pk; pk.x = p0; pk.y = p1;
    *(uint2*)op = pk;
}

// ---------------------------------------------------------------------------
// Tiled transpose + cast fp32 -> bf16.  out[r][c] = in[c][r], zero-padded.
// grid: (outC/32, outR/32), block (32,8).  outR/outC multiples of 32.
// ---------------------------------------------------------------------------
__global__ __launch_bounds__(256)
void tcast_k(const float* __restrict__ in, int R, int C,
             u16* __restrict__ out, int outC) {
    __shared__ float t[32][33];
    const int r0 = blockIdx.y * 32;   // out row base (= input col)
    const int c0 = blockIdx.x * 32;   // out col base (= input row)
    const int tx = threadIdx.x, ty = threadIdx.y;
#pragma unroll
    for (int j = 0; j < 4; ++j) {
        int ir = c0 + ty + j * 8;     // input row
        int ic = r0 + tx;             // input col
        t[ty + j * 8][tx] = (ir < R && ic < C) ? in[(size_t)ir * C + ic] : 0.0f;
    }
    __syncthreads();
#pragma unroll
    for (int j = 0; j < 4; ++j) {
        out[(size_t)(r0 + ty + j * 8) * outC + c0 + tx] = f2b(t[tx][ty + j * 8]);
    }
}

// ---------------------------------------------------------------------------
// V transpose per head: vt[h][d][t] = vb[t][h*64+d]   (bf16 -> bf16)
// grid: (S/32, DK/32, H), block (32,8)
// ---------------------------------------------------------------------------
__global__ __launch_bounds__(256)
void vtrans_k(const u16* __restrict__ vb, u16* __restrict__ vt) {
    __shared__ u16 t[32][33];
    const int h = blockIdx.z;
    const int t0 = blockIdx.x * 32;   // sequence pos base (out col)
    const int d0 = blockIdx.y * 32;   // head-dim base (out row)
    const int tx = threadIdx.x, ty = threadIdx.y;
#pragma unroll
    for (int j = 0; j < 4; ++j)
        t[ty + j * 8][tx] = vb[(size_t)(t0 + ty + j * 8) * D_MODEL + h * DK + d0 + tx];
    __syncthreads();
#pragma unroll
    for (int j = 0; j < 4; ++j)
        vt[(size_t)h * DK * S_LEN + (size_t)(d0 + ty + j * 8) * S_LEN + t0 + tx] =
            t[tx][ty + j * 8];
}

// ---------------------------------------------------------------------------
// RoPE in place on qb and kb (bf16), pairs (even,odd).
// ---------------------------------------------------------------------------
__global__ __launch_bounds__(256)
void rope_k(u16* __restrict__ q, u16* __restrict__ k,
            const float* __restrict__ fc, const float* __restrict__ fs) {
    const int idx = blockIdx.x * 256 + threadIdx.x;   // S*H*32 total
    const int s = idx >> 9;
    const int rem = idx & 511;
    const int h = rem >> 5;
    const int i = rem & 31;
    const size_t base = (size_t)s * D_MODEL + h * DK + 2 * i;
    const float c = fc[s * 32 + i], sn = fs[s * 32 + i];
    float t0 = b2f(q[base]), t1 = b2f(q[base + 1]);
    q[base]     = f2b(t0 * c - t1 * sn);
    q[base + 1] = f2b(t0 * sn + t1 * c);
    t0 = b2f(k[base]); t1 = b2f(k[base + 1]);
    k[base]     = f2b(t0 * c - t1 * sn);
    k[base + 1] = f2b(t0 * sn + t1 * c);
}

// ---------------------------------------------------------------------------
// Row softmax over 4096 bf16 logits, in place. grid (S, z)
// ---------------------------------------------------------------------------
__global__ __launch_bounds__(256)
void softmax_k(u16* __restrict__ p, long long zstride) {
    u16* row = p + (size_t)blockIdx.y * zstride + (size_t)blockIdx.x * S_LEN;
    const int tid = threadIdx.x;
    uint4 u0 = ((const uint4*)row)[tid];
    uint4 u1 = ((const uint4*)row)[tid + 256];
    u32 w[8] = {u0.x, u0.y, u0.z, u0.w, u1.x, u1.y, u1.z, u1.w};
    float v[16];
#pragma unroll
    for (int q = 0; q < 8; ++q) {
        v[2 * q]     = __builtin_bit_cast(float, w[q] << 16);
        v[2 * q + 1] = __builtin_bit_cast(float, w[q] & 0xFFFF0000u);
    }
    float m = -1e30f;
#pragma unroll
    for (int i = 0; i < 16; ++i) m = fmaxf(m, v[i]);
    __shared__ float red[4];
    const int lane = tid & 63, wv = tid >> 6;
    for (int o = 32; o; o >>= 1) m = fmaxf(m, __shfl_down(m, o));
    if (lane == 0) red[wv] = m;
    __syncthreads();
    m = fmaxf(fmaxf(red[0], red[1]), fmaxf(red[2], red[3]));
    __syncthreads();
    float s = 0.f;
#pragma unroll
    for (int i = 0; i < 16; ++i) { v[i] = expf(v[i] - m); s += v[i]; }
    for (int o = 32; o; o >>= 1) s += __shfl_down(s, o);
    if (lane == 0) red[wv] = s;
    __syncthreads();
    s = red[0] + red[1] + red[2] + red[3];
    const float inv = 1.0f / s;
#pragma unroll
    for (int q = 0; q < 8; ++q)
        w[q] = (u32)f2b(v[2 * q] * inv) | ((u32)f2b(v[2 * q + 1] * inv) << 16);
    ((uint4*)row)[tid]       = make_uint4(w[0], w[1], w[2], w[3]);
    ((uint4*)row)[tid + 256] = make_uint4(w[4], w[5], w[6], w[7]);
}

// ---------------------------------------------------------------------------
// GEMM: C = A @ Bt^T.  A: M x K (row stride lda, k-contig bf16)
//       Bt: N x K (row stride ldb, k-contig bf16)
// Block tile 64x64, 4 waves (each 16 rows x 64 cols), K-step 32.
// EPI 0: store bf16.  EPI 1: scores (scale + causal mask, bf16).
// EPI 2: fp32 out = resid + acc.
// grid (N/64, M/64, Z); per-Z strides in elements.
// ---------------------------------------------------------------------------
template <int EPI>
__global__ __launch_bounds__(256)
void gemm_bt(const u16* __restrict__ A, int lda, long long strideA,
             const u16* __restrict__ Bt, int ldb, long long strideB,
             void* __restrict__ C, int ldc, long long strideC,
             int K, float scale, const float* __restrict__ resid) {
    const int m0 = blockIdx.y * 64;
    const int n0 = blockIdx.x * 64;
    A  += (size_t)blockIdx.z * strideA;
    Bt += (size_t)blockIdx.z * strideB;
    const int tid = threadIdx.x;
    const int wave = tid >> 6, lane = tid & 63;
    const int r16 = lane & 15, kq = lane >> 4;

    if (EPI == 1 && n0 > m0 + 63) {   // fully-masked tile: emit -1e9, skip GEMM
        u16* Cb = (u16*)C + (size_t)blockIdx.z * strideC;
        const u16 nv = f2b(-1e9f);
#pragma unroll
        for (int nt = 0; nt < 4; ++nt) {
            int col = n0 + nt * 16 + r16;
#pragma unroll
            for (int j = 0; j < 4; ++j)
                Cb[(size_t)(m0 + wave * 16 + kq * 4 + j) * ldc + col] = nv;
        }
        return;
    }

    __shared__ __align__(16) u16 As[64][40];
    __shared__ __align__(16) u16 Bs[64][40];

    const int ldRow = tid >> 2;
    const int ldK = (tid & 3) << 3;
    const u16* aptr = A + (size_t)(m0 + ldRow) * lda + ldK;
    const u16* bptr = Bt + (size_t)(n0 + ldRow) * ldb + ldK;

    f32x4 acc[4];
    const f32x4 zero = {0.f, 0.f, 0.f, 0.f};
#pragma unroll
    for (int nt = 0; nt < 4; ++nt) acc[nt] = zero;

    for (int k0 = 0; k0 < K; k0 += 32) {
        const uint4 av = *(const uint4*)(aptr + k0);
        const uint4 bv = *(const uint4*)(bptr + k0);
        __syncthreads();
        *(uint4*)&As[ldRow][ldK] = av;
        *(uint4*)&Bs[ldRow][ldK] = bv;
        __syncthreads();
        const bf16x8 a = *(const bf16x8*)&As[wave * 16 + r16][kq * 8];
#pragma unroll
        for (int nt = 0; nt < 4; ++nt) {
            const bf16x8 b = *(const bf16x8*)&Bs[nt * 16 + r16][kq * 8];
            acc[nt] = __builtin_amdgcn_mfma_f32_16x16x32_bf16(a, b, acc[nt], 0, 0, 0);
        }
    }

    if (EPI == 0 || EPI == 1) {
        u16* Cb = (u16*)C + (size_t)blockIdx.z * strideC;
#pragma unroll
        for (int nt = 0; nt < 4; ++nt) {
            int col = n0 + nt * 16 + r16;
#pragma unroll
            for (int j = 0; j < 4; ++j) {
                int row = m0 + wave * 16 + kq * 4 + j;
                float v = acc[nt][j];
                if (EPI == 1) v = v * scale + ((col <= row) ? 0.f : -1e9f);
                Cb[(size_t)row * ldc + col] = f2b(v);
            }
        }
    } else {
        float* Cf = (float*)C;
#pragma unroll
        for (int nt = 0; nt < 4; ++nt) {
            int col = n0 + nt * 16 + r16;
#pragma unroll
            for (int j = 0; j < 4; ++j) {
                int row = m0 + wave * 16 + kq * 4 + j;
                Cf[(size_t)row * ldc + col] =
                    resid[(size_t)row * ldc + col] + acc[nt][j];
            }
        }
    }
}

// ---------------------------------------------------------------------------
// Dual GEMM for FFN: ff = silu(A@w1t^T) * (A@w3t^T), bf16 out, tile 64x64
// ---------------------------------------------------------------------------
__global__ __launch_bounds__(256)
void gemm_dual(const u16* __restrict__ A, int lda,
               const u16* __restrict__ B1, const u16* __restrict__ B3, int ldb,
               u16* __restrict__ C, int ldc, int K) {
    const int m0 = blockIdx.y * 64;
    const int n0 = blockIdx.x * 64;
    const int tid = threadIdx.x;
    const int wave = tid >> 6, lane = tid & 63;
    const int r16 = lane & 15, kq = lane >> 4;

    __shared__ __align__(16) u16 As[64][40];
    __shared__ __align__(16) u16 B1s[64][40];
    __shared__ __align__(16) u16 B3s[64][40];

    const int ldRow = tid >> 2;
    const int ldK = (tid & 3) << 3;
    const u16* aptr = A + (size_t)(m0 + ldRow) * lda + ldK;
    const u16* b1p = B1 + (size_t)(n0 + ldRow) * ldb + ldK;
    const u16* b3p = B3 + (size_t)(n0 + ldRow) * ldb + ldK;

    f32x4 acc1[4], acc3[4];
    const f32x4 zero = {0.f, 0.f, 0.f, 0.f};
#pragma unroll
    for (int nt = 0; nt < 4; ++nt) { acc1[nt] = zero; acc3[nt] = zero; }

    for (int k0 = 0; k0 < K; k0 += 32) {
        const uint4 av = *(const uint4*)(aptr + k0);
        const uint4 b1v = *(const uint4*)(b1p + k0);
        const uint4 b3v = *(const uint4*)(b3p + k0);
        __syncthreads();
        *(uint4*)&As[ldRow][ldK] = av;
        *(uint4*)&B1s[ldRow][ldK] = b1v;
        *(uint4*)&B3s[ldRow][ldK] = b3v;
        __syncthreads();
        const bf16x8 a = *(const bf16x8*)&As[wave * 16 + r16][kq * 8];
#pragma unroll
        for (int nt = 0; nt < 4; ++nt) {
            const bf16x8 b1 = *(const bf16x8*)&B1s[nt * 16 + r16][kq * 8];
            acc1[nt] = __builtin_amdgcn_mfma_f32_16x16x32_bf16(a, b1, acc1[nt], 0, 0, 0);
            const bf16x8 b3 = *(const bf16x8*)&B3s[nt * 16 + r16][kq * 8];
            acc3[nt] = __builtin_amdgcn_mfma_f32_16x16x32_bf16(a, b3, acc3[nt], 0, 0, 0);
        }
    }

#pragma unroll
    for (int nt = 0; nt < 4; ++nt) {
        int col = n0 + nt * 16 + r16;
#pragma unroll
        for (int j = 0; j < 4; ++j) {
            int row = m0 + wave * 16 + kq * 4 + j;
            float v1 = acc1[nt][j], v3 = acc3[nt][j];
            float sig = 1.0f / (1.0f + expf(-v1));
            C[(size_t)row * ldc + col] = f2b(v1 * sig * v3);
        }
    }
}

// ---------------------------------------------------------------------------
extern "C" void kernel_launch(void* const* d_in, const int* in_sizes, int n_in,
                              void* d_out, int out_size, void* d_ws, size_t ws_size,
                              hipStream_t stream) {
    const float* x    = (const float*)d_in[0];
    const float* fcos = (const float*)d_in[1];
    const float* fsin = (const float*)d_in[2];
    // d_in[3] = mask (unused; causal mask applied analytically)
    const float* Wq = (const float*)d_in[4];
    const float* Wk = (const float*)d_in[5];
    const float* Wv = (const float*)d_in[6];
    const float* Wo = (const float*)d_in[7];
    const float* ln1 = (const float*)d_in[8];
    const float* ln2 = (const float*)d_in[9];
    const float* w1 = (const float*)d_in[10];
    const float* w2 = (const float*)d_in[11];
    const float* w3 = (const float*)d_in[12];
    float* out = (float*)d_out;

    char* ws = (char*)d_ws;
    size_t off = 0;
    auto alloc = [&](size_t bytes) -> char* {
        char* p = ws + off;
        off += (bytes + 255) & ~(size_t)255;
        return p;
    };
    u16* hb   = (u16*)alloc((size_t)S_LEN * D_MODEL * 2);
    u16* wqt  = (u16*)alloc((size_t)D_MODEL * D_MODEL * 2);
    u16* wkt  = (u16*)alloc((size_t)D_MODEL * D_MODEL * 2);
    u16* wvt  = (u16*)alloc((size_t)D_MODEL * D_MODEL * 2);
    u16* wot  = (u16*)alloc((size_t)D_MODEL * D_MODEL * 2);
    u16* qb   = (u16*)alloc((size_t)S_LEN * D_MODEL * 2);
    u16* kb   = (u16*)alloc((size_t)S_LEN * D_MODEL * 2);
    u16* vb   = (u16*)alloc((size_t)S_LEN * D_MODEL * 2);
    u16* vt   = (u16*)alloc((size_t)S_LEN * D_MODEL * 2);   // [H][DK][S]
    u16* ctxb = (u16*)alloc((size_t)S_LEN * D_MODEL * 2);
    float* x2 = (float*)alloc((size_t)S_LEN * D_MODEL * 4);
    u16* h2b  = (u16*)alloc((size_t)S_LEN * D_MODEL * 2);
    u16* w1t  = (u16*)alloc((size_t)HIDP * D_MODEL * 2);
    u16* w3t  = (u16*)alloc((size_t)HIDP * D_MODEL * 2);
    u16* w2t  = (u16*)alloc((size_t)D_MODEL * HIDP * 2);
    u16* ffb  = (u16*)alloc((size_t)S_LEN * HIDP * 2);
    const size_t baseNeed = off;
    u16* sb = (u16*)(ws + baseNeed);

    const size_t attnBytes = (size_t)S_LEN * S_LEN * 2;   // 32 MB per head
    int zcap = 1;
    if (ws_size > baseNeed) {
        size_t z = (ws_size - baseNeed) / attnBytes;
        zcap = (z < 1) ? 1 : (z > 16 ? 16 : (int)z);
    }

    const dim3 tb32(32, 8);

    // weight transposes (fp32 -> bf16, Bt layout)
    tcast_k<<<dim3(32, 32), tb32, 0, stream>>>(Wq, D_MODEL, D_MODEL, wqt, D_MODEL);
    tcast_k<<<dim3(32, 32), tb32, 0, stream>>>(Wk, D_MODEL, D_MODEL, wkt, D_MODEL);
    tcast_k<<<dim3(32, 32), tb32, 0, stream>>>(Wv, D_MODEL, D_MODEL, wvt, D_MODEL);
    tcast_k<<<dim3(32, 32), tb32, 0, stream>>>(Wo, D_MODEL, D_MODEL, wot, D_MODEL);
    tcast_k<<<dim3(32, HIDP / 32), tb32, 0, stream>>>(w1, D_MODEL, HID, w1t, D_MODEL);
    tcast_k<<<dim3(32, HIDP / 32), tb32, 0, stream>>>(w3, D_MODEL, HID, w3t, D_MODEL);
    tcast_k<<<dim3(HIDP / 32, 32), tb32, 0, stream>>>(w2, HID, D_MODEL, w2t, HIDP);

    // h = rmsnorm(x, ln1)
    rmsnorm_k<<<S_LEN, 256, 0, stream>>>(x, ln1, hb);

    // Q, K, V = h @ W{q,k,v}
    gemm_bt<0><<<dim3(16, 64, 1), 256, 0, stream>>>(hb, D_MODEL, 0, wqt, D_MODEL, 0,
                                                    qb, D_MODEL, 0, D_MODEL, 0.f, nullptr);
    gemm_bt<0><<<dim3(16, 64, 1), 256, 0, stream>>>(hb, D_MODEL, 0, wkt, D_MODEL, 0,
                                                    kb, D_MODEL, 0, D_MODEL, 0.f, nullptr);
    gemm_bt<0><<<dim3(16, 64, 1), 256, 0, stream>>>(hb, D_MODEL, 0, wvt, D_MODEL, 0,
                                                    vb, D_MODEL, 0, D_MODEL, 0.f, nullptr);

    // RoPE on Q, K (in place)
    rope_k<<<(S_LEN * NHEAD * 32) / 256, 256, 0, stream>>>(qb, kb, fcos, fsin);

    // V transposed per head for ctx GEMM
    vtrans_k<<<dim3(S_LEN / 32, DK / 32, NHEAD), tb32, 0, stream>>>(vb, vt);

    // attention, heads batched zcap at a time through the score buffer
    for (int g0 = 0; g0 < NHEAD; g0 += zcap) {
        const int z = (NHEAD - g0 < zcap) ? (NHEAD - g0) : zcap;
        gemm_bt<1><<<dim3(64, 64, z), 256, 0, stream>>>(
            qb + g0 * DK, D_MODEL, DK, kb + g0 * DK, D_MODEL, DK,
            sb, S_LEN, (long long)S_LEN * S_LEN, DK, 0.125f, nullptr);
        softmax_k<<<dim3(S_LEN, z), 256, 0, stream>>>(sb, (long long)S_LEN * S_LEN);
        gemm_bt<0><<<dim3(1, 64, z), 256, 0, stream>>>(
            sb, S_LEN, (long long)S_LEN * S_LEN,
            vt + (size_t)g0 * DK * S_LEN, S_LEN, (long long)DK * S_LEN,
            ctxb + g0 * DK, D_MODEL, DK, S_LEN, 0.f, nullptr);
    }

    // x2 = x + ctx @ Wo
    gemm_bt<2><<<dim3(16, 64, 1), 256, 0, stream>>>(ctxb, D_MODEL, 0, wot, D_MODEL, 0,
                                                    x2, D_MODEL, 0, D_MODEL, 0.f, x);

    // h2 = rmsnorm(x2, ln2)
    rmsnorm_k<<<S_LEN, 256, 0, stream>>>(x2, ln2, h2b);

    // ff = silu(h2@w1) * (h2@w3)
    gemm_dual<<<dim3(HIDP / 64, 64, 1), 256, 0, stream>>>(h2b, D_MODEL, w1t, w3t,
                                                          D_MODEL, ffb, HIDP, D_MODEL);

    // out = x2 + ff @ w2
    gemm_bt<2><<<dim3(16, 64, 1), 256, 0, stream>>>(ffb, HIDP, 0, w2t, HIDP, 0,
                                                    out, D_MODEL, 0, HIDP, 0.f, x2);
}

// Round 3
// 627.127 us; speedup vs baseline: 1.4796x; 1.4796x over previous
//
#include <hip/hip_runtime.h>

#define S_LEN 4096
#define D_MODEL 1024
#define NHEAD 16
#define DK 64
#define HID 2730
#define HIDP 2816
#define QKV_LD 3072

typedef unsigned short u16;
typedef unsigned int u32;
typedef __bf16 bf16x8 __attribute__((ext_vector_type(8)));
typedef float f32x4 __attribute__((ext_vector_type(4)));

#define MFMA16 __builtin_amdgcn_mfma_f32_16x16x32_bf16

__device__ __forceinline__ float b2f(u16 u) {
    return __builtin_bit_cast(float, (u32)u << 16);
}
__device__ __forceinline__ u16 f2b(float f) {
    u32 u = __builtin_bit_cast(u32, f);
    u += 0x7FFF + ((u >> 16) & 1);
    return (u16)(u >> 16);
}
// async global->LDS, 16B per lane; dest = lds base (wave-uniform) + lane*16
__device__ __forceinline__ void gll16(const u16* g, u16* l) {
    __builtin_amdgcn_global_load_lds(
        (__attribute__((address_space(1))) void*)(g),
        (__attribute__((address_space(3))) void*)(l),
        16, 0, 0);
}

// ---------------------------------------------------------------------------
// RMSNorm: one block per row (D=1024), fp32 in -> bf16 out
// ---------------------------------------------------------------------------
__global__ __launch_bounds__(256)
void rmsnorm_k(const float* __restrict__ x, const float* __restrict__ w,
               u16* __restrict__ out) {
    const int row = blockIdx.x;
    const int tid = threadIdx.x;
    const float4 v = ((const float4*)(x + (size_t)row * D_MODEL))[tid];
    float ss = v.x * v.x + v.y * v.y + v.z * v.z + v.w * v.w;
    for (int o = 32; o; o >>= 1) ss += __shfl_down(ss, o);
    __shared__ float red[4];
    if ((tid & 63) == 0) red[tid >> 6] = ss;
    __syncthreads();
    const float tot = red[0] + red[1] + red[2] + red[3];
    const float rs = rsqrtf(tot * (1.0f / D_MODEL) + 1e-6f);
    const float4 wv = ((const float4*)w)[tid];
    u16* op = out + (size_t)row * D_MODEL + tid * 4;
    u32 p0 = (u32)f2b(v.x * rs * wv.x) | ((u32)f2b(v.y * rs * wv.y) << 16);
    u32 p1 = (u32)f2b(v.z * rs * wv.z) | ((u32)f2b(v.w * rs * wv.w) << 16);
    uint2 pk; pk.x = p0; pk.y = p1;
    *(uint2*)op = pk;
}

// ---------------------------------------------------------------------------
// Tiled transpose + cast fp32 -> bf16.  out[r][c] = in[c][r], zero-padded.
// ---------------------------------------------------------------------------
__global__ __launch_bounds__(256)
void tcast_k(const float* __restrict__ in, int R, int C,
             u16* __restrict__ out, int outC) {
    __shared__ float t[32][33];
    const int r0 = blockIdx.y * 32;
    const int c0 = blockIdx.x * 32;
    const int tx = threadIdx.x, ty = threadIdx.y;
#pragma unroll
    for (int j = 0; j < 4; ++j) {
        int ir = c0 + ty + j * 8;
        int ic = r0 + tx;
        t[ty + j * 8][tx] = (ir < R && ic < C) ? in[(size_t)ir * C + ic] : 0.0f;
    }
    __syncthreads();
#pragma unroll
    for (int j = 0; j < 4; ++j)
        out[(size_t)(r0 + ty + j * 8) * outC + c0 + tx] = f2b(t[tx][ty + j * 8]);
}

// ---------------------------------------------------------------------------
// V transpose per head: vt[h][d][t] = qkv[t][2*D_MODEL + h*64 + d]
// grid: (S/32, DK/32, H), block (32,8)
// ---------------------------------------------------------------------------
__global__ __launch_bounds__(256)
void vtrans_k(const u16* __restrict__ vb, u16* __restrict__ vt) {
    __shared__ u16 t[32][33];
    const int h = blockIdx.z;
    const int t0 = blockIdx.x * 32;
    const int d0 = blockIdx.y * 32;
    const int tx = threadIdx.x, ty = threadIdx.y;
#pragma unroll
    for (int j = 0; j < 4; ++j)
        t[ty + j * 8][tx] =
            vb[(size_t)(t0 + ty + j * 8) * QKV_LD + 2 * D_MODEL + h * DK + d0 + tx];
    __syncthreads();
#pragma unroll
    for (int j = 0; j < 4; ++j)
        vt[(size_t)h * DK * S_LEN + (size_t)(d0 + ty + j * 8) * S_LEN + t0 + tx] =
            t[tx][ty + j * 8];
}

// ---------------------------------------------------------------------------
// RoPE in place on Q and K halves of qkv buffer (row stride 3072)
// ---------------------------------------------------------------------------
__global__ __launch_bounds__(256)
void rope_k(u16* __restrict__ qkv, const float* __restrict__ fc,
            const float* __restrict__ fs) {
    const int idx = blockIdx.x * 256 + threadIdx.x;   // S*H*32 total
    const int s = idx >> 9;
    const int rem = idx & 511;
    const int h = rem >> 5;
    const int i = rem & 31;
    const size_t base = (size_t)s * QKV_LD + h * DK + 2 * i;
    const float c = fc[s * 32 + i], sn = fs[s * 32 + i];
    u16* q = qkv + base;
    u16* k = qkv + base + D_MODEL;
    float t0 = b2f(q[0]), t1 = b2f(q[1]);
    q[0] = f2b(t0 * c - t1 * sn);
    q[1] = f2b(t0 * sn + t1 * c);
    t0 = b2f(k[0]); t1 = b2f(k[1]);
    k[0] = f2b(t0 * c - t1 * sn);
    k[1] = f2b(t0 * sn + t1 * c);
}

// ---------------------------------------------------------------------------
// 128x128 GEMM (m97 structure): C = A @ Bt^T, global_load_lds staging.
// A: M x K (lda, k-contig bf16), Bt: N x K (ldb, k-contig bf16).
// 4 waves; wave (wr,wc) owns a 64x64 quadrant as 4x4 16x16 MFMA tiles.
// EPI 0: bf16 store.  EPI 2: fp32 out = resid + acc.
// ---------------------------------------------------------------------------
template <int EPI>
__global__ __launch_bounds__(256)
void gemm128(const u16* __restrict__ A, int lda, const u16* __restrict__ Bt, int ldb,
             void* __restrict__ C, int ldc, int K, const float* __restrict__ resid) {
    const int m0 = blockIdx.y * 128, n0 = blockIdx.x * 128;
    const int tid = threadIdx.x;
    const int wave = tid >> 6, lane = tid & 63;
    const int wr = wave >> 1, wc = wave & 1;
    const int r16 = lane & 15, kq = lane >> 4;

    __shared__ __align__(16) u16 As[128 * 32];
    __shared__ __align__(16) u16 Bs[128 * 32];

    const int srow = tid >> 2, sk = (tid & 3) * 8;
    const u16* ag0 = A + (size_t)(m0 + srow) * lda + sk;
    const u16* ag1 = A + (size_t)(m0 + 64 + srow) * lda + sk;
    const u16* bg0 = Bt + (size_t)(n0 + srow) * ldb + sk;
    const u16* bg1 = Bt + (size_t)(n0 + 64 + srow) * ldb + sk;
    u16* asw = As + wave * 512;
    u16* bsw = Bs + wave * 512;

    f32x4 acc[16];
#pragma unroll
    for (int i = 0; i < 16; ++i) acc[i] = f32x4{0.f, 0.f, 0.f, 0.f};

    for (int k0 = 0; k0 < K; k0 += 32) {
        __syncthreads();
        gll16(ag0 + k0, asw);
        gll16(ag1 + k0, asw + 2048);
        gll16(bg0 + k0, bsw);
        gll16(bg1 + k0, bsw + 2048);
        __syncthreads();
        bf16x8 af[4], bf[4];
#pragma unroll
        for (int mt = 0; mt < 4; ++mt)
            af[mt] = *(const bf16x8*)&As[(wr * 64 + mt * 16 + r16) * 32 + kq * 8];
#pragma unroll
        for (int nt = 0; nt < 4; ++nt)
            bf[nt] = *(const bf16x8*)&Bs[(wc * 64 + nt * 16 + r16) * 32 + kq * 8];
#pragma unroll
        for (int mt = 0; mt < 4; ++mt)
#pragma unroll
            for (int nt = 0; nt < 4; ++nt)
                acc[mt * 4 + nt] = MFMA16(af[mt], bf[nt], acc[mt * 4 + nt], 0, 0, 0);
    }

#pragma unroll
    for (int mt = 0; mt < 4; ++mt) {
#pragma unroll
        for (int nt = 0; nt < 4; ++nt) {
            const int col = n0 + wc * 64 + nt * 16 + r16;
#pragma unroll
            for (int j = 0; j < 4; ++j) {
                const int row = m0 + wr * 64 + mt * 16 + kq * 4 + j;
                if (EPI == 0) {
                    ((u16*)C)[(size_t)row * ldc + col] = f2b(acc[mt * 4 + nt][j]);
                } else {
                    ((float*)C)[(size_t)row * ldc + col] =
                        resid[(size_t)row * ldc + col] + acc[mt * 4 + nt][j];
                }
            }
        }
    }
}

// ---------------------------------------------------------------------------
// FFN dual GEMM: tile 128(M) x 64(N per matrix); ff = silu(A@B1^T)*(A@B3^T)
// ---------------------------------------------------------------------------
__global__ __launch_bounds__(256)
void gemm_dual64(const u16* __restrict__ A, int lda,
                 const u16* __restrict__ B1, const u16* __restrict__ B3, int ldb,
                 u16* __restrict__ C, int ldc, int K) {
    const int m0 = blockIdx.y * 128, n0 = blockIdx.x * 64;
    const int tid = threadIdx.x;
    const int wave = tid >> 6, lane = tid & 63;
    const int r16 = lane & 15, kq = lane >> 4;

    __shared__ __align__(16) u16 As[128 * 32];
    __shared__ __align__(16) u16 B1s[64 * 32];
    __shared__ __align__(16) u16 B3s[64 * 32];

    const int srow = tid >> 2, sk = (tid & 3) * 8;
    const u16* ag0 = A + (size_t)(m0 + srow) * lda + sk;
    const u16* ag1 = A + (size_t)(m0 + 64 + srow) * lda + sk;
    const u16* b1g = B1 + (size_t)(n0 + srow) * ldb + sk;
    const u16* b3g = B3 + (size_t)(n0 + srow) * ldb + sk;
    u16* asw = As + wave * 512;
    u16* b1w = B1s + wave * 512;
    u16* b3w = B3s + wave * 512;

    f32x4 acc1[8], acc3[8];
#pragma unroll
    for (int i = 0; i < 8; ++i) {
        acc1[i] = f32x4{0.f, 0.f, 0.f, 0.f};
        acc3[i] = f32x4{0.f, 0.f, 0.f, 0.f};
    }

    for (int k0 = 0; k0 < K; k0 += 32) {
        __syncthreads();
        gll16(ag0 + k0, asw);
        gll16(ag1 + k0, asw + 2048);
        gll16(b1g + k0, b1w);
        gll16(b3g + k0, b3w);
        __syncthreads();
        bf16x8 af[2], b1f[4], b3f[4];
#pragma unroll
        for (int mt = 0; mt < 2; ++mt)
            af[mt] = *(const bf16x8*)&As[(wave * 32 + mt * 16 + r16) * 32 + kq * 8];
#pragma unroll
        for (int nt = 0; nt < 4; ++nt) {
            b1f[nt] = *(const bf16x8*)&B1s[(nt * 16 + r16) * 32 + kq * 8];
            b3f[nt] = *(const bf16x8*)&B3s[(nt * 16 + r16) * 32 + kq * 8];
        }
#pragma unroll
        for (int mt = 0; mt < 2; ++mt)
#pragma unroll
            for (int nt = 0; nt < 4; ++nt) {
                acc1[mt * 4 + nt] = MFMA16(af[mt], b1f[nt], acc1[mt * 4 + nt], 0, 0, 0);
                acc3[mt * 4 + nt] = MFMA16(af[mt], b3f[nt], acc3[mt * 4 + nt], 0, 0, 0);
            }
    }

#pragma unroll
    for (int mt = 0; mt < 2; ++mt)
#pragma unroll
        for (int nt = 0; nt < 4; ++nt) {
            const int col = n0 + nt * 16 + r16;
#pragma unroll
            for (int j = 0; j < 4; ++j) {
                const int row = m0 + wave * 32 + mt * 16 + kq * 4 + j;
                const float v1 = acc1[mt * 4 + nt][j];
                const float v3 = acc3[mt * 4 + nt][j];
                const float sig = 1.0f / (1.0f + __expf(-v1));
                C[(size_t)row * ldc + col] = f2b(v1 * sig * v3);
            }
        }
}

// ---------------------------------------------------------------------------
// Flash attention: one block = 64 Q rows x 1 head; iterate causal KV tiles.
// Online softmax; P converts C-layout -> A-layout via LDS round-trip.
// ---------------------------------------------------------------------------
__global__ __launch_bounds__(256)
void flash_k(const u16* __restrict__ qkv, const u16* __restrict__ vt,
             u16* __restrict__ ctx) {
    const int h = blockIdx.y;
    const int qi = 63 - (int)blockIdx.x;     // longest blocks dispatch first
    const int q0 = qi * 64;
    const int tid = threadIdx.x;
    const int wave = tid >> 6, lane = tid & 63;
    const int r16 = lane & 15, kq = lane >> 4;

    __shared__ __align__(16) u16 Ks[64][72];   // [kv row][dk]
    __shared__ __align__(16) u16 Vs[64][72];   // [dk][kv row]  (from vt)
    __shared__ __align__(16) u16 Ps[4][16][72];

    const u16* qrow = qkv + (size_t)(q0 + wave * 16 + r16) * QKV_LD + h * DK;
    const bf16x8 qf0 = *(const bf16x8*)(qrow + kq * 8);
    const bf16x8 qf1 = *(const bf16x8*)(qrow + 32 + kq * 8);

    f32x4 o[4];
#pragma unroll
    for (int i = 0; i < 4; ++i) o[i] = f32x4{0.f, 0.f, 0.f, 0.f};
    float mrun[4] = {-1e30f, -1e30f, -1e30f, -1e30f};
    float lrun[4] = {0.f, 0.f, 0.f, 0.f};

    const u16* kbase = qkv + D_MODEL + h * DK;
    const u16* vbase = vt + (size_t)h * DK * S_LEN;

    for (int t = 0; t <= qi; ++t) {
        const int t0 = t * 64;
        __syncthreads();
#pragma unroll
        for (int i = 0; i < 2; ++i) {
            const int id = tid + i * 256;
            const int r = id >> 3, c = (id & 7) * 8;
            *(uint4*)&Ks[r][c] = *(const uint4*)(kbase + (size_t)(t0 + r) * QKV_LD + c);
            *(uint4*)&Vs[r][c] = *(const uint4*)(vbase + (size_t)r * S_LEN + t0 + c);
        }
        __syncthreads();

        f32x4 s[4];
#pragma unroll
        for (int nt = 0; nt < 4; ++nt) {
            s[nt] = f32x4{0.f, 0.f, 0.f, 0.f};
            const bf16x8 b0 = *(const bf16x8*)&Ks[nt * 16 + r16][kq * 8];
            s[nt] = MFMA16(qf0, b0, s[nt], 0, 0, 0);
            const bf16x8 b1 = *(const bf16x8*)&Ks[nt * 16 + r16][32 + kq * 8];
            s[nt] = MFMA16(qf1, b1, s[nt], 0, 0, 0);
        }

        const bool diag = (t == qi);
        float p[4][4];
#pragma unroll
        for (int j = 0; j < 4; ++j) {
            const int rloc = wave * 16 + kq * 4 + j;
            float pj[4];
            float lm = -1e30f;
#pragma unroll
            for (int nt = 0; nt < 4; ++nt) {
                float v = s[nt][j] * 0.125f;
                if (diag && (nt * 16 + r16) > rloc) v = -1e9f;
                pj[nt] = v;
                lm = fmaxf(lm, v);
            }
#pragma unroll
            for (int o2 = 1; o2 < 16; o2 <<= 1) lm = fmaxf(lm, __shfl_xor(lm, o2));
            const float mnew = fmaxf(mrun[j], lm);
            const float alpha = __expf(mrun[j] - mnew);
            mrun[j] = mnew;
            float rs = 0.f;
#pragma unroll
            for (int nt = 0; nt < 4; ++nt) {
                const float e = __expf(pj[nt] - mnew);
                p[nt][j] = e;
                rs += e;
            }
#pragma unroll
            for (int o2 = 1; o2 < 16; o2 <<= 1) rs += __shfl_xor(rs, o2);
            lrun[j] = lrun[j] * alpha + rs;
#pragma unroll
            for (int nt = 0; nt < 4; ++nt) o[nt][j] *= alpha;
        }

#pragma unroll
        for (int nt = 0; nt < 4; ++nt)
#pragma unroll
            for (int j = 0; j < 4; ++j)
                Ps[wave][kq * 4 + j][nt * 16 + r16] = f2b(p[nt][j]);
        __syncthreads();

#pragma unroll
        for (int ks = 0; ks < 2; ++ks) {
            const bf16x8 a = *(const bf16x8*)&Ps[wave][r16][ks * 32 + kq * 8];
#pragma unroll
            for (int nt = 0; nt < 4; ++nt) {
                const bf16x8 b = *(const bf16x8*)&Vs[nt * 16 + r16][ks * 32 + kq * 8];
                o[nt] = MFMA16(a, b, o[nt], 0, 0, 0);
            }
        }
    }

#pragma unroll
    for (int j = 0; j < 4; ++j) {
        const float inv = 1.0f / lrun[j];
        const size_t row = q0 + wave * 16 + kq * 4 + j;
#pragma unroll
        for (int nt = 0; nt < 4; ++nt)
            ctx[row * D_MODEL + h * DK + nt * 16 + r16] = f2b(o[nt][j] * inv);
    }
}

// ---------------------------------------------------------------------------
extern "C" void kernel_launch(void* const* d_in, const int* in_sizes, int n_in,
                              void* d_out, int out_size, void* d_ws, size_t ws_size,
                              hipStream_t stream) {
    const float* x    = (const float*)d_in[0];
    const float* fcos = (const float*)d_in[1];
    const float* fsin = (const float*)d_in[2];
    const float* Wq = (const float*)d_in[4];
    const float* Wk = (const float*)d_in[5];
    const float* Wv = (const float*)d_in[6];
    const float* Wo = (const float*)d_in[7];
    const float* ln1 = (const float*)d_in[8];
    const float* ln2 = (const float*)d_in[9];
    const float* w1 = (const float*)d_in[10];
    const float* w2 = (const float*)d_in[11];
    const float* w3 = (const float*)d_in[12];
    float* out = (float*)d_out;

    char* ws = (char*)d_ws;
    size_t off = 0;
    auto alloc = [&](size_t bytes) -> char* {
        char* p = ws + off;
        off += (bytes + 255) & ~(size_t)255;
        return p;
    };
    u16* hb    = (u16*)alloc((size_t)S_LEN * D_MODEL * 2);
    u16* wqkvt = (u16*)alloc((size_t)QKV_LD * D_MODEL * 2);  // [3072][1024]
    u16* wot   = (u16*)alloc((size_t)D_MODEL * D_MODEL * 2);
    u16* qkvb  = (u16*)alloc((size_t)S_LEN * QKV_LD * 2);    // [4096][3072]
    u16* vt    = (u16*)alloc((size_t)S_LEN * D_MODEL * 2);   // [H][DK][S]
    u16* ctxb  = (u16*)alloc((size_t)S_LEN * D_MODEL * 2);
    float* x2  = (float*)alloc((size_t)S_LEN * D_MODEL * 4);
    u16* h2b   = (u16*)alloc((size_t)S_LEN * D_MODEL * 2);
    u16* w1t   = (u16*)alloc((size_t)HIDP * D_MODEL * 2);    // [2816][1024]
    u16* w3t   = (u16*)alloc((size_t)HIDP * D_MODEL * 2);
    u16* w2t   = (u16*)alloc((size_t)D_MODEL * HIDP * 2);    // [1024][2816]
    u16* ffb   = (u16*)alloc((size_t)S_LEN * HIDP * 2);      // [4096][2816]

    const dim3 tb32(32, 8);

    // weight transposes (fp32 -> bf16, N x K layout); QKV concatenated
    tcast_k<<<dim3(32, 32), tb32, 0, stream>>>(Wq, D_MODEL, D_MODEL, wqkvt, D_MODEL);
    tcast_k<<<dim3(32, 32), tb32, 0, stream>>>(Wk, D_MODEL, D_MODEL,
                                               wqkvt + (size_t)D_MODEL * D_MODEL, D_MODEL);
    tcast_k<<<dim3(32, 32), tb32, 0, stream>>>(Wv, D_MODEL, D_MODEL,
                                               wqkvt + (size_t)2 * D_MODEL * D_MODEL, D_MODEL);
    tcast_k<<<dim3(32, 32), tb32, 0, stream>>>(Wo, D_MODEL, D_MODEL, wot, D_MODEL);
    tcast_k<<<dim3(32, HIDP / 32), tb32, 0, stream>>>(w1, D_MODEL, HID, w1t, D_MODEL);
    tcast_k<<<dim3(32, HIDP / 32), tb32, 0, stream>>>(w3, D_MODEL, HID, w3t, D_MODEL);
    tcast_k<<<dim3(HIDP / 32, 32), tb32, 0, stream>>>(w2, HID, D_MODEL, w2t, HIDP);

    // h = rmsnorm(x, ln1)
    rmsnorm_k<<<S_LEN, 256, 0, stream>>>(x, ln1, hb);

    // QKV = h @ [Wq|Wk|Wv]   (one 4096x3072x1024 GEMM)
    gemm128<0><<<dim3(QKV_LD / 128, S_LEN / 128), 256, 0, stream>>>(
        hb, D_MODEL, wqkvt, D_MODEL, qkvb, QKV_LD, D_MODEL, nullptr);

    // RoPE on Q,K halves
    rope_k<<<(S_LEN * NHEAD * 32) / 256, 256, 0, stream>>>(qkvb, fcos, fsin);

    // V transposed per head
    vtrans_k<<<dim3(S_LEN / 32, DK / 32, NHEAD), tb32, 0, stream>>>(qkvb, vt);

    // flash attention
    flash_k<<<dim3(S_LEN / 64, NHEAD), 256, 0, stream>>>(qkvb, vt, ctxb);

    // x2 = x + ctx @ Wo
    gemm128<2><<<dim3(D_MODEL / 128, S_LEN / 128), 256, 0, stream>>>(
        ctxb, D_MODEL, wot, D_MODEL, x2, D_MODEL, D_MODEL, x);

    // h2 = rmsnorm(x2, ln2)
    rmsnorm_k<<<S_LEN, 256, 0, stream>>>(x2, ln2, h2b);

    // ff = silu(h2@w1) * (h2@w3)
    gemm_dual64<<<dim3(HIDP / 64, S_LEN / 128), 256, 0, stream>>>(
        h2b, D_MODEL, w1t, w3t, D_MODEL, ffb, HIDP, D_MODEL);

    // out = x2 + ff @ w2
    gemm128<2><<<dim3(D_MODEL / 128, S_LEN / 128), 256, 0, stream>>>(
        ffb, HIDP, w2t, HIDP, out, D_MODEL, HIDP, x2);
}

// Round 4
// 497.601 us; speedup vs baseline: 1.8648x; 1.2603x over previous
//
#include <hip/hip_runtime.h>

#define S_LEN 4096
#define D_MODEL 1024
#define NHEAD 16
#define DK 64
#define HID 2730
#define HIDP 2816
#define QKV_LD 3072

typedef unsigned short u16;
typedef unsigned int u32;
typedef __bf16 bf16x8 __attribute__((ext_vector_type(8)));
typedef float f32x4 __attribute__((ext_vector_type(4)));

#define MFMA16 __builtin_amdgcn_mfma_f32_16x16x32_bf16

__device__ __forceinline__ float b2f(u16 u) {
    return __builtin_bit_cast(float, (u32)u << 16);
}
__device__ __forceinline__ u16 f2b(float f) {
    u32 u = __builtin_bit_cast(u32, f);
    u += 0x7FFF + ((u >> 16) & 1);
    return (u16)(u >> 16);
}
// async global->LDS, 16B per lane; dest = lds base (wave-uniform) + lane*16
__device__ __forceinline__ void gll16(const u16* g, u16* l) {
    __builtin_amdgcn_global_load_lds(
        (__attribute__((address_space(1))) void*)(g),
        (__attribute__((address_space(3))) void*)(l),
        16, 0, 0);
}

// ---------------------------------------------------------------------------
// RMSNorm: one block per row (D=1024), fp32 in -> bf16 out
// ---------------------------------------------------------------------------
__global__ __launch_bounds__(256)
void rmsnorm_k(const float* __restrict__ x, const float* __restrict__ w,
               u16* __restrict__ out) {
    const int row = blockIdx.x;
    const int tid = threadIdx.x;
    const float4 v = ((const float4*)(x + (size_t)row * D_MODEL))[tid];
    float ss = v.x * v.x + v.y * v.y + v.z * v.z + v.w * v.w;
    for (int o = 32; o; o >>= 1) ss += __shfl_down(ss, o);
    __shared__ float red[4];
    if ((tid & 63) == 0) red[tid >> 6] = ss;
    __syncthreads();
    const float tot = red[0] + red[1] + red[2] + red[3];
    const float rs = rsqrtf(tot * (1.0f / D_MODEL) + 1e-6f);
    const float4 wv = ((const float4*)w)[tid];
    u16* op = out + (size_t)row * D_MODEL + tid * 4;
    u32 p0 = (u32)f2b(v.x * rs * wv.x) | ((u32)f2b(v.y * rs * wv.y) << 16);
    u32 p1 = (u32)f2b(v.z * rs * wv.z) | ((u32)f2b(v.w * rs * wv.w) << 16);
    uint2 pk; pk.x = p0; pk.y = p1;
    *(uint2*)op = pk;
}

// ---------------------------------------------------------------------------
// Tiled transpose + cast fp32 -> bf16.  out[r][c] = in[c][r], zero-padded.
// ---------------------------------------------------------------------------
__global__ __launch_bounds__(256)
void tcast_k(const float* __restrict__ in, int R, int C,
             u16* __restrict__ out, int outC) {
    __shared__ float t[32][33];
    const int r0 = blockIdx.y * 32;
    const int c0 = blockIdx.x * 32;
    const int tx = threadIdx.x, ty = threadIdx.y;
#pragma unroll
    for (int j = 0; j < 4; ++j) {
        int ir = c0 + ty + j * 8;
        int ic = r0 + tx;
        t[ty + j * 8][tx] = (ir < R && ic < C) ? in[(size_t)ir * C + ic] : 0.0f;
    }
    __syncthreads();
#pragma unroll
    for (int j = 0; j < 4; ++j)
        out[(size_t)(r0 + ty + j * 8) * outC + c0 + tx] = f2b(t[tx][ty + j * 8]);
}

// ---------------------------------------------------------------------------
// V transpose per head: vt[h][d][t] = qkv[t][2*D_MODEL + h*64 + d]
// grid: (S/32, DK/32, H), block (32,8)
// ---------------------------------------------------------------------------
__global__ __launch_bounds__(256)
void vtrans_k(const u16* __restrict__ vb, u16* __restrict__ vt) {
    __shared__ u16 t[32][33];
    const int h = blockIdx.z;
    const int t0 = blockIdx.x * 32;
    const int d0 = blockIdx.y * 32;
    const int tx = threadIdx.x, ty = threadIdx.y;
#pragma unroll
    for (int j = 0; j < 4; ++j)
        t[ty + j * 8][tx] =
            vb[(size_t)(t0 + ty + j * 8) * QKV_LD + 2 * D_MODEL + h * DK + d0 + tx];
    __syncthreads();
#pragma unroll
    for (int j = 0; j < 4; ++j)
        vt[(size_t)h * DK * S_LEN + (size_t)(d0 + ty + j * 8) * S_LEN + t0 + tx] =
            t[tx][ty + j * 8];
}

// ---------------------------------------------------------------------------
// RoPE in place on Q and K halves of qkv buffer (row stride 3072)
// ---------------------------------------------------------------------------
__global__ __launch_bounds__(256)
void rope_k(u16* __restrict__ qkv, const float* __restrict__ fc,
            const float* __restrict__ fs) {
    const int idx = blockIdx.x * 256 + threadIdx.x;   // S*H*32 total
    const int s = idx >> 9;
    const int rem = idx & 511;
    const int h = rem >> 5;
    const int i = rem & 31;
    const size_t base = (size_t)s * QKV_LD + h * DK + 2 * i;
    const float c = fc[s * 32 + i], sn = fs[s * 32 + i];
    u16* q = qkv + base;
    u16* k = qkv + base + D_MODEL;
    float t0 = b2f(q[0]), t1 = b2f(q[1]);
    q[0] = f2b(t0 * c - t1 * sn);
    q[1] = f2b(t0 * sn + t1 * c);
    t0 = b2f(k[0]); t1 = b2f(k[1]);
    k[0] = f2b(t0 * c - t1 * sn);
    k[1] = f2b(t0 * sn + t1 * c);
}

// ---------------------------------------------------------------------------
// 128x128 GEMM (m97 structure): C = A @ Bt^T, global_load_lds staging.
// ---------------------------------------------------------------------------
template <int EPI>
__global__ __launch_bounds__(256)
void gemm128(const u16* __restrict__ A, int lda, const u16* __restrict__ Bt, int ldb,
             void* __restrict__ C, int ldc, int K, const float* __restrict__ resid) {
    const int m0 = blockIdx.y * 128, n0 = blockIdx.x * 128;
    const int tid = threadIdx.x;
    const int wave = tid >> 6, lane = tid & 63;
    const int wr = wave >> 1, wc = wave & 1;
    const int r16 = lane & 15, kq = lane >> 4;

    __shared__ __align__(16) u16 As[128 * 32];
    __shared__ __align__(16) u16 Bs[128 * 32];

    const int srow = tid >> 2, sk = (tid & 3) * 8;
    const u16* ag0 = A + (size_t)(m0 + srow) * lda + sk;
    const u16* ag1 = A + (size_t)(m0 + 64 + srow) * lda + sk;
    const u16* bg0 = Bt + (size_t)(n0 + srow) * ldb + sk;
    const u16* bg1 = Bt + (size_t)(n0 + 64 + srow) * ldb + sk;
    u16* asw = As + wave * 512;
    u16* bsw = Bs + wave * 512;

    f32x4 acc[16];
#pragma unroll
    for (int i = 0; i < 16; ++i) acc[i] = f32x4{0.f, 0.f, 0.f, 0.f};

    for (int k0 = 0; k0 < K; k0 += 32) {
        __syncthreads();
        gll16(ag0 + k0, asw);
        gll16(ag1 + k0, asw + 2048);
        gll16(bg0 + k0, bsw);
        gll16(bg1 + k0, bsw + 2048);
        __syncthreads();
        bf16x8 af[4], bf[4];
#pragma unroll
        for (int mt = 0; mt < 4; ++mt)
            af[mt] = *(const bf16x8*)&As[(wr * 64 + mt * 16 + r16) * 32 + kq * 8];
#pragma unroll
        for (int nt = 0; nt < 4; ++nt)
            bf[nt] = *(const bf16x8*)&Bs[(wc * 64 + nt * 16 + r16) * 32 + kq * 8];
#pragma unroll
        for (int mt = 0; mt < 4; ++mt)
#pragma unroll
            for (int nt = 0; nt < 4; ++nt)
                acc[mt * 4 + nt] = MFMA16(af[mt], bf[nt], acc[mt * 4 + nt], 0, 0, 0);
    }

#pragma unroll
    for (int mt = 0; mt < 4; ++mt) {
#pragma unroll
        for (int nt = 0; nt < 4; ++nt) {
            const int col = n0 + wc * 64 + nt * 16 + r16;
#pragma unroll
            for (int j = 0; j < 4; ++j) {
                const int row = m0 + wr * 64 + mt * 16 + kq * 4 + j;
                if (EPI == 0) {
                    ((u16*)C)[(size_t)row * ldc + col] = f2b(acc[mt * 4 + nt][j]);
                } else {
                    ((float*)C)[(size_t)row * ldc + col] =
                        resid[(size_t)row * ldc + col] + acc[mt * 4 + nt][j];
                }
            }
        }
    }
}

// ---------------------------------------------------------------------------
// FFN dual GEMM: tile 128(M) x 64(N per matrix); ff = silu(A@B1^T)*(A@B3^T)
// ---------------------------------------------------------------------------
__global__ __launch_bounds__(256)
void gemm_dual64(const u16* __restrict__ A, int lda,
                 const u16* __restrict__ B1, const u16* __restrict__ B3, int ldb,
                 u16* __restrict__ C, int ldc, int K) {
    const int m0 = blockIdx.y * 128, n0 = blockIdx.x * 64;
    const int tid = threadIdx.x;
    const int wave = tid >> 6, lane = tid & 63;
    const int r16 = lane & 15, kq = lane >> 4;

    __shared__ __align__(16) u16 As[128 * 32];
    __shared__ __align__(16) u16 B1s[64 * 32];
    __shared__ __align__(16) u16 B3s[64 * 32];

    const int srow = tid >> 2, sk = (tid & 3) * 8;
    const u16* ag0 = A + (size_t)(m0 + srow) * lda + sk;
    const u16* ag1 = A + (size_t)(m0 + 64 + srow) * lda + sk;
    const u16* b1g = B1 + (size_t)(n0 + srow) * ldb + sk;
    const u16* b3g = B3 + (size_t)(n0 + srow) * ldb + sk;
    u16* asw = As + wave * 512;
    u16* b1w = B1s + wave * 512;
    u16* b3w = B3s + wave * 512;

    f32x4 acc1[8], acc3[8];
#pragma unroll
    for (int i = 0; i < 8; ++i) {
        acc1[i] = f32x4{0.f, 0.f, 0.f, 0.f};
        acc3[i] = f32x4{0.f, 0.f, 0.f, 0.f};
    }

    for (int k0 = 0; k0 < K; k0 += 32) {
        __syncthreads();
        gll16(ag0 + k0, asw);
        gll16(ag1 + k0, asw + 2048);
        gll16(b1g + k0, b1w);
        gll16(b3g + k0, b3w);
        __syncthreads();
        bf16x8 af[2], b1f[4], b3f[4];
#pragma unroll
        for (int mt = 0; mt < 2; ++mt)
            af[mt] = *(const bf16x8*)&As[(wave * 32 + mt * 16 + r16) * 32 + kq * 8];
#pragma unroll
        for (int nt = 0; nt < 4; ++nt) {
            b1f[nt] = *(const bf16x8*)&B1s[(nt * 16 + r16) * 32 + kq * 8];
            b3f[nt] = *(const bf16x8*)&B3s[(nt * 16 + r16) * 32 + kq * 8];
        }
#pragma unroll
        for (int mt = 0; mt < 2; ++mt)
#pragma unroll
            for (int nt = 0; nt < 4; ++nt) {
                acc1[mt * 4 + nt] = MFMA16(af[mt], b1f[nt], acc1[mt * 4 + nt], 0, 0, 0);
                acc3[mt * 4 + nt] = MFMA16(af[mt], b3f[nt], acc3[mt * 4 + nt], 0, 0, 0);
            }
    }

#pragma unroll
    for (int mt = 0; mt < 2; ++mt)
#pragma unroll
        for (int nt = 0; nt < 4; ++nt) {
            const int col = n0 + nt * 16 + r16;
#pragma unroll
            for (int j = 0; j < 4; ++j) {
                const int row = m0 + wave * 32 + mt * 16 + kq * 4 + j;
                const float v1 = acc1[mt * 4 + nt][j];
                const float v3 = acc3[mt * 4 + nt][j];
                const float sig = 1.0f / (1.0f + __expf(-v1));
                C[(size_t)row * ldc + col] = f2b(v1 * sig * v3);
            }
        }
}

// ---------------------------------------------------------------------------
// Flash attention, S^T formulation.
// Block = (pair, head); processes q-tiles {pair, 63-pair} -> uniform 65 tiles.
// S^T = MFMA(K_frag, Q_frag): D[kv][q], col=q=r16 -> per-lane softmax state.
// O^T = MFMA(Vt_frag, Pt_frag): D[d][q], col=q=r16 -> lane-local rescale.
// ---------------------------------------------------------------------------
__global__ __launch_bounds__(256)
void flash_k(const u16* __restrict__ qkv, const u16* __restrict__ vt,
             u16* __restrict__ ctx) {
    const int h = blockIdx.y;
    const int pair = blockIdx.x;              // 0..31
    const int tid = threadIdx.x;
    const int wave = tid >> 6, lane = tid & 63;
    const int r16 = lane & 15, kq = lane >> 4;

    __shared__ __align__(16) u16 Ks[64][72];   // [kv row][dk]
    __shared__ __align__(16) u16 Vs[64][72];   // [dk][kv row]  (from vt)
    __shared__ __align__(16) u16 Ps[4][16][72]; // per-wave: [q][kv]

    const u16* kbase = qkv + D_MODEL + h * DK;
    const u16* vbase = vt + (size_t)h * DK * S_LEN;

    for (int half = 0; half < 2; ++half) {
        const int qi = half ? (63 - pair) : pair;
        const int q0 = qi * 64;

        const u16* qrow = qkv + (size_t)(q0 + wave * 16 + r16) * QKV_LD + h * DK;
        const bf16x8 qf0 = *(const bf16x8*)(qrow + kq * 8);
        const bf16x8 qf1 = *(const bf16x8*)(qrow + 32 + kq * 8);

        f32x4 o[4];
#pragma unroll
        for (int i = 0; i < 4; ++i) o[i] = f32x4{0.f, 0.f, 0.f, 0.f};
        float mrun = -1e30f, lrun = 0.f;

        for (int t = 0; t <= qi; ++t) {
            const int t0 = t * 64;
            __syncthreads();
#pragma unroll
            for (int i = 0; i < 2; ++i) {
                const int id = tid + i * 256;
                const int r = id >> 3, c = (id & 7) * 8;
                *(uint4*)&Ks[r][c] = *(const uint4*)(kbase + (size_t)(t0 + r) * QKV_LD + c);
                *(uint4*)&Vs[r][c] = *(const uint4*)(vbase + (size_t)r * S_LEN + t0 + c);
            }
            __syncthreads();

            // S^T[kv][q]: A = K rows, B = Q rows
            f32x4 s[4];
#pragma unroll
            for (int nt = 0; nt < 4; ++nt) {
                s[nt] = f32x4{0.f, 0.f, 0.f, 0.f};
                const bf16x8 k0 = *(const bf16x8*)&Ks[nt * 16 + r16][kq * 8];
                s[nt] = MFMA16(k0, qf0, s[nt], 0, 0, 0);
                const bf16x8 k1 = *(const bf16x8*)&Ks[nt * 16 + r16][32 + kq * 8];
                s[nt] = MFMA16(k1, qf1, s[nt], 0, 0, 0);
            }

            // per-lane softmax for column q = r16 (16 kv values in regs)
            const bool diag = (t == qi);
            const int qloc = wave * 16 + r16;
            float v[16];
#pragma unroll
            for (int nt = 0; nt < 4; ++nt)
#pragma unroll
                for (int j = 0; j < 4; ++j) {
                    float sv = s[nt][j] * 0.125f;
                    if (diag && (nt * 16 + kq * 4 + j) > qloc) sv = -1e9f;
                    v[nt * 4 + j] = sv;
                }
            float red[8];
#pragma unroll
            for (int i = 0; i < 8; ++i) red[i] = fmaxf(v[2 * i], v[2 * i + 1]);
#pragma unroll
            for (int w2 = 4; w2; w2 >>= 1)
#pragma unroll
                for (int i = 0; i < 8; ++i)
                    if (i < w2) red[i] = fmaxf(red[2 * i], red[2 * i + 1]);
            float lm = red[0];
            lm = fmaxf(lm, __shfl_xor(lm, 16));
            lm = fmaxf(lm, __shfl_xor(lm, 32));
            const float mnew = fmaxf(mrun, lm);
            const float alpha = __expf(mrun - mnew);
            mrun = mnew;
#pragma unroll
            for (int i = 0; i < 16; ++i) v[i] = __expf(v[i] - mnew);
#pragma unroll
            for (int i = 0; i < 8; ++i) red[i] = v[2 * i] + v[2 * i + 1];
#pragma unroll
            for (int w2 = 4; w2; w2 >>= 1)
#pragma unroll
                for (int i = 0; i < 8; ++i)
                    if (i < w2) red[i] = red[2 * i] + red[2 * i + 1];
            float rs = red[0];
            rs += __shfl_xor(rs, 16);
            rs += __shfl_xor(rs, 32);
            lrun = lrun * alpha + rs;
#pragma unroll
            for (int nt = 0; nt < 4; ++nt) o[nt] *= alpha;

            // P^T -> per-wave LDS as Ps[q][kv] (packed 8B writes; no barrier:
            // wave-private buffer, in-wave DS ordering suffices)
#pragma unroll
            for (int nt = 0; nt < 4; ++nt) {
                uint2 pk;
                pk.x = (u32)f2b(v[nt * 4 + 0]) | ((u32)f2b(v[nt * 4 + 1]) << 16);
                pk.y = (u32)f2b(v[nt * 4 + 2]) | ((u32)f2b(v[nt * 4 + 3]) << 16);
                *(uint2*)&Ps[wave][r16][nt * 16 + kq * 4] = pk;
            }

            // O^T += V^T @ P^T : A = Vs rows (d), B = Ps rows (q)
#pragma unroll
            for (int ks = 0; ks < 2; ++ks) {
                const bf16x8 pf = *(const bf16x8*)&Ps[wave][r16][ks * 32 + kq * 8];
#pragma unroll
                for (int nt = 0; nt < 4; ++nt) {
                    const bf16x8 vf = *(const bf16x8*)&Vs[nt * 16 + r16][ks * 32 + kq * 8];
                    o[nt] = MFMA16(vf, pf, o[nt], 0, 0, 0);
                }
            }
        }

        // store: lane owns col q = r16, rows d = nt*16 + kq*4 + j
        const float inv = 1.0f / lrun;
        const size_t row = q0 + wave * 16 + r16;
#pragma unroll
        for (int nt = 0; nt < 4; ++nt) {
            uint2 pk;
            pk.x = (u32)f2b(o[nt][0] * inv) | ((u32)f2b(o[nt][1] * inv) << 16);
            pk.y = (u32)f2b(o[nt][2] * inv) | ((u32)f2b(o[nt][3] * inv) << 16);
            *(uint2*)&ctx[row * D_MODEL + h * DK + nt * 16 + kq * 4] = pk;
        }
    }
}

// ---------------------------------------------------------------------------
extern "C" void kernel_launch(void* const* d_in, const int* in_sizes, int n_in,
                              void* d_out, int out_size, void* d_ws, size_t ws_size,
                              hipStream_t stream) {
    const float* x    = (const float*)d_in[0];
    const float* fcos = (const float*)d_in[1];
    const float* fsin = (const float*)d_in[2];
    const float* Wq = (const float*)d_in[4];
    const float* Wk = (const float*)d_in[5];
    const float* Wv = (const float*)d_in[6];
    const float* Wo = (const float*)d_in[7];
    const float* ln1 = (const float*)d_in[8];
    const float* ln2 = (const float*)d_in[9];
    const float* w1 = (const float*)d_in[10];
    const float* w2 = (const float*)d_in[11];
    const float* w3 = (const float*)d_in[12];
    float* out = (float*)d_out;

    char* ws = (char*)d_ws;
    size_t off = 0;
    auto alloc = [&](size_t bytes) -> char* {
        char* p = ws + off;
        off += (bytes + 255) & ~(size_t)255;
        return p;
    };
    u16* hb    = (u16*)alloc((size_t)S_LEN * D_MODEL * 2);
    u16* wqkvt = (u16*)alloc((size_t)QKV_LD * D_MODEL * 2);  // [3072][1024]
    u16* wot   = (u16*)alloc((size_t)D_MODEL * D_MODEL * 2);
    u16* qkvb  = (u16*)alloc((size_t)S_LEN * QKV_LD * 2);    // [4096][3072]
    u16* vt    = (u16*)alloc((size_t)S_LEN * D_MODEL * 2);   // [H][DK][S]
    u16* ctxb  = (u16*)alloc((size_t)S_LEN * D_MODEL * 2);
    float* x2  = (float*)alloc((size_t)S_LEN * D_MODEL * 4);
    u16* h2b   = (u16*)alloc((size_t)S_LEN * D_MODEL * 2);
    u16* w1t   = (u16*)alloc((size_t)HIDP * D_MODEL * 2);    // [2816][1024]
    u16* w3t   = (u16*)alloc((size_t)HIDP * D_MODEL * 2);
    u16* w2t   = (u16*)alloc((size_t)D_MODEL * HIDP * 2);    // [1024][2816]
    u16* ffb   = (u16*)alloc((size_t)S_LEN * HIDP * 2);      // [4096][2816]

    const dim3 tb32(32, 8);

    // weight transposes (fp32 -> bf16, N x K layout); QKV concatenated
    tcast_k<<<dim3(32, 32), tb32, 0, stream>>>(Wq, D_MODEL, D_MODEL, wqkvt, D_MODEL);
    tcast_k<<<dim3(32, 32), tb32, 0, stream>>>(Wk, D_MODEL, D_MODEL,
                                               wqkvt + (size_t)D_MODEL * D_MODEL, D_MODEL);
    tcast_k<<<dim3(32, 32), tb32, 0, stream>>>(Wv, D_MODEL, D_MODEL,
                                               wqkvt + (size_t)2 * D_MODEL * D_MODEL, D_MODEL);
    tcast_k<<<dim3(32, 32), tb32, 0, stream>>>(Wo, D_MODEL, D_MODEL, wot, D_MODEL);
    tcast_k<<<dim3(32, HIDP / 32), tb32, 0, stream>>>(w1, D_MODEL, HID, w1t, D_MODEL);
    tcast_k<<<dim3(32, HIDP / 32), tb32, 0, stream>>>(w3, D_MODEL, HID, w3t, D_MODEL);
    tcast_k<<<dim3(HIDP / 32, 32), tb32, 0, stream>>>(w2, HID, D_MODEL, w2t, HIDP);

    // h = rmsnorm(x, ln1)
    rmsnorm_k<<<S_LEN, 256, 0, stream>>>(x, ln1, hb);

    // QKV = h @ [Wq|Wk|Wv]   (one 4096x3072x1024 GEMM)
    gemm128<0><<<dim3(QKV_LD / 128, S_LEN / 128), 256, 0, stream>>>(
        hb, D_MODEL, wqkvt, D_MODEL, qkvb, QKV_LD, D_MODEL, nullptr);

    // RoPE on Q,K halves
    rope_k<<<(S_LEN * NHEAD * 32) / 256, 256, 0, stream>>>(qkvb, fcos, fsin);

    // V transposed per head
    vtrans_k<<<dim3(S_LEN / 32, DK / 32, NHEAD), tb32, 0, stream>>>(qkvb, vt);

    // flash attention (paired q-tiles -> uniform work)
    flash_k<<<dim3(32, NHEAD), 256, 0, stream>>>(qkvb, vt, ctxb);

    // x2 = x + ctx @ Wo
    gemm128<2><<<dim3(D_MODEL / 128, S_LEN / 128), 256, 0, stream>>>(
        ctxb, D_MODEL, wot, D_MODEL, x2, D_MODEL, D_MODEL, x);

    // h2 = rmsnorm(x2, ln2)
    rmsnorm_k<<<S_LEN, 256, 0, stream>>>(x2, ln2, h2b);

    // ff = silu(h2@w1) * (h2@w3)
    gemm_dual64<<<dim3(HIDP / 64, S_LEN / 128), 256, 0, stream>>>(
        h2b, D_MODEL, w1t, w3t, D_MODEL, ffb, HIDP, D_MODEL);

    // out = x2 + ff @ w2
    gemm128<2><<<dim3(D_MODEL / 128, S_LEN / 128), 256, 0, stream>>>(
        ffb, HIDP, w2t, HIDP, out, D_MODEL, HIDP, x2);
}